// Round 1
// baseline (496.914 us; speedup 1.0000x reference)
//
#include <hip/hip_runtime.h>
#include <stdint.h>

#define NR 16
#define NC 80
#define NA 8400
#define NB 16
#define KPRE 1024
#define MAXDET 300
#define CONF_T 0.25f
#define IOU_THR 0.45f

// Robust scalar read: harness passes python ints most likely as int32; fall
// back to float32 reinterpretation if the int pattern is implausible.
__device__ __forceinline__ float read_dim(const void* p) {
  int iv = *(const int*)p;
  return (iv > 0 && iv < (1 << 20)) ? (float)iv : *(const float*)p;
}

// ---------------------------------------------------------------- decode ----
__global__ __launch_bounds__(256) void k_decode(
    const float* __restrict__ p0, const float* __restrict__ p1,
    const float* __restrict__ p2, const void* __restrict__ hp,
    const void* __restrict__ wp, float4* __restrict__ boxes,
    int* __restrict__ labels, uint32_t* __restrict__ keys) {
  int gid = blockIdx.x * 256 + threadIdx.x;
  if (gid >= NB * NA) return;
  int b = gid / NA, a = gid - b * NA;
  const float* p; int HW, W; float stride; int m;
  if (a < 6400)      { p = p0; HW = 6400; W = 80; stride = 8.f;  m = a; }
  else if (a < 8000) { p = p1; HW = 1600; W = 40; stride = 16.f; m = a - 6400; }
  else               { p = p2; HW = 400;  W = 20; stride = 32.f; m = a - 8000; }
  const float* base = p + (size_t)b * (4 * NR + NC) * HW + m;

  // DFL: softmax-expectation over 16 bins for each of l,t,r,b
  float d[4];
#pragma unroll
  for (int k = 0; k < 4; ++k) {
    float v[NR]; float mx = -3.4e38f;
#pragma unroll
    for (int r = 0; r < NR; ++r) { v[r] = base[(k * NR + r) * HW]; mx = fmaxf(mx, v[r]); }
    float se = 0.f, sn = 0.f;
#pragma unroll
    for (int r = 0; r < NR; ++r) { float e = expf(v[r] - mx); se += e; sn += e * (float)r; }
    d[k] = sn / se * stride;
  }
  int x = m % W, y = m / W;
  float cx = ((float)x + 0.5f) * stride, cy = ((float)y + 0.5f) * stride;
  float hx = read_dim(wp) - 1.f, hy = read_dim(hp) - 1.f;
  float x1 = fminf(fmaxf(cx - d[0], 0.f), hx);
  float y1 = fminf(fmaxf(cy - d[1], 0.f), hy);
  float x2 = fminf(fmaxf(cx + d[2], 0.f), hx);
  float y2 = fminf(fmaxf(cy + d[3], 0.f), hy);
  boxes[gid] = make_float4(x1, y1, x2, y2);

  // class max / argmax on raw logits (sigmoid monotone; strict > = first idx)
  float ml = base[(4 * NR) * HW]; int mc = 0;
#pragma unroll 4
  for (int c = 1; c < NC; ++c) {
    float v = base[(4 * NR + c) * HW];
    if (v > ml) { ml = v; mc = c; }
  }
  labels[gid] = mc;
  float smax = 1.f / (1.f + expf(-ml));
  float s = smax > CONF_T ? smax : -1.0f;
  uint32_t bt = __float_as_uint(s);
  keys[gid] = (bt & 0x80000000u) ? ~bt : (bt | 0x80000000u);  // order-preserving
}

// -------------------------------------------------------- rank-based topk ---
// Exact stable top-K: rank(c) = #{ j : key64_j > key64_c }, with
// key64 = (u32key << 32) | (0xFFFFFFFF - index)  (desc score, asc index).
// Keys are unique => ranks are a permutation; rank < 1024 selects & sorts.
__global__ __launch_bounds__(256) void k_rank(
    const uint32_t* __restrict__ keys, const float4* __restrict__ boxes,
    const int* __restrict__ labels, float4* __restrict__ selbox,
    float4* __restrict__ selboff, float* __restrict__ selscore,
    int* __restrict__ sellab) {
  __shared__ __align__(16) uint32_t sk[NA];
  int img = blockIdx.y;
  const uint32_t* kb = keys + img * NA;
  for (int j = threadIdx.x; j < NA; j += 256) sk[j] = kb[j];
  __syncthreads();

  int c0 = blockIdx.x * 512 + threadIdx.x * 2;  // two candidates per thread
  bool a0 = c0 < NA, a1 = (c0 + 1) < NA;
  uint64_t kc0 = 0, kc1 = 0;
  if (a0) kc0 = ((uint64_t)sk[c0] << 32) | (uint64_t)(0xFFFFFFFFu - (uint32_t)c0);
  if (a1) kc1 = ((uint64_t)sk[c0 + 1] << 32) | (uint64_t)(0xFFFFFFFFu - (uint32_t)(c0 + 1));
  int n0 = 0, n1 = 0;
  for (int j = 0; j < NA; j += 4) {
    uint4 q = *(const uint4*)&sk[j];          // wave-uniform addr: LDS broadcast
    uint32_t jj = 0xFFFFFFFFu - (uint32_t)j;
    uint64_t k0 = ((uint64_t)q.x << 32) | (uint64_t)jj;
    uint64_t k1 = ((uint64_t)q.y << 32) | (uint64_t)(jj - 1u);
    uint64_t k2 = ((uint64_t)q.z << 32) | (uint64_t)(jj - 2u);
    uint64_t k3 = ((uint64_t)q.w << 32) | (uint64_t)(jj - 3u);
    n0 += (int)(k0 > kc0) + (int)(k1 > kc0) + (int)(k2 > kc0) + (int)(k3 > kc0);
    n1 += (int)(k0 > kc1) + (int)(k1 > kc1) + (int)(k2 > kc1) + (int)(k3 > kc1);
  }
#pragma unroll
  for (int t = 0; t < 2; ++t) {
    int c = c0 + t; int rk = t ? n1 : n0; bool ok = t ? a1 : a0;
    if (ok && rk < KPRE) {
      float4 bx = boxes[img * NA + c];
      int lab = labels[img * NA + c];
      uint32_t uc = sk[c];
      uint32_t bits = (uc & 0x80000000u) ? (uc & 0x7FFFFFFFu) : ~uc;
      float s = __uint_as_float(bits);
      float off = (float)lab * 4096.0f;  // replicate reference CLS_OFFSET fp math
      int o = img * KPRE + rk;
      selbox[o] = bx;
      selboff[o] = make_float4(bx.x + off, bx.y + off, bx.z + off, bx.w + off);
      selscore[o] = s;
      sellab[o] = lab;
    }
  }
}

// ----------------------------------------------------- IoU suppression bits -
__global__ __launch_bounds__(256) void k_iou(const float4* __restrict__ selboff,
                                             uint64_t* __restrict__ rowmask) {
  __shared__ float4 bb[KPRE];
  int img = blockIdx.y;
  for (int j = threadIdx.x; j < KPRE; j += 256) bb[j] = selboff[img * KPRE + j];
  __syncthreads();
  int i = blockIdx.x * 16 + (threadIdx.x >> 4);
  int w = threadIdx.x & 15;
  float4 bi = bb[i];
  float ai = (bi.z - bi.x) * (bi.w - bi.y);
  uint64_t bits = 0;
  for (int jj = 0; jj < 64; ++jj) {
    int j = w * 64 + jj;
    float4 bj = bb[j];
    float lx = fmaxf(bi.x, bj.x), ly = fmaxf(bi.y, bj.y);
    float rx = fminf(bi.z, bj.z), ry = fminf(bi.w, bj.w);
    float iw = fmaxf(rx - lx, 0.f), ih = fmaxf(ry - ly, 0.f);
    float inter = iw * ih;
    float aj = (bj.z - bj.x) * (bj.w - bj.y);
    float iou = inter / (ai + aj - inter + 1e-7f);
    bits |= (uint64_t)((iou > IOU_THR) && (j != i)) << jj;
  }
  rowmask[(size_t)(img * KPRE + i) * 16 + w] = bits;
}

// ------------------------------------------------------ serial greedy scan --
__global__ __launch_bounds__(64) void k_scan(
    const uint64_t* __restrict__ rowmask, const float* __restrict__ selbox_f,
    const float* __restrict__ selscore, const int* __restrict__ sellab,
    float* __restrict__ out) {
  __shared__ float lsc[KPRE];
  __shared__ uint64_t rows[64 * 16];
  int img = blockIdx.x;
  int lane = threadIdx.x;
  for (int j = lane; j < KPRE; j += 64) lsc[j] = selscore[img * KPRE + j];
  __syncthreads();

  float* ob = out;                        // (B,300,4)
  float* os = out + NB * MAXDET * 4;      // (B,300)
  float* ol = out + NB * MAXDET * 5;      // (B,300) labels as float
  float* ov = out + NB * MAXDET * 6;      // (B,300) valid as 0/1 float

  uint64_t remv = 0;  // lane t<16 owns 64-bit word t of the 1024-bit mask
  int n = 0;
  for (int chunk = 0; chunk < 16 && n < MAXDET; ++chunk) {
    const uint64_t* g = rowmask + (size_t)(img * KPRE + chunk * 64) * 16;
    for (int k2 = lane; k2 < 1024; k2 += 64) rows[k2] = g[k2];
    __syncthreads();
    for (int ii = 0; ii < 64; ++ii) {
      int i = chunk * 64 + ii;
      int supbit = (int)((remv >> ii) & 1ull);
      supbit = __shfl(supbit, chunk);  // word index of bit i is exactly `chunk`
      if (!supbit && lsc[i] > CONF_T) {
        remv |= (lane < 16) ? rows[ii * 16 + lane] : 0ull;
        if (lane < 4)       ob[(size_t)(img * MAXDET + n) * 4 + lane] =
                                selbox_f[(size_t)(img * KPRE + i) * 4 + lane];
        else if (lane == 4) os[img * MAXDET + n] = lsc[i];
        else if (lane == 5) ol[img * MAXDET + n] = (float)sellab[img * KPRE + i];
        n++;
        if (n == MAXDET) break;
      }
    }
    __syncthreads();
  }
  for (int slot = lane; slot < MAXDET; slot += 64) {
    ov[img * MAXDET + slot] = (slot < n) ? 1.0f : 0.0f;
    if (slot >= n) {
      os[img * MAXDET + slot] = 0.0f;
      ol[img * MAXDET + slot] = -1.0f;
      float* bp = ob + (size_t)(img * MAXDET + slot) * 4;
      bp[0] = 0.f; bp[1] = 0.f; bp[2] = 0.f; bp[3] = 0.f;
    }
  }
}

// -------------------------------------------------------------- launcher ----
extern "C" void kernel_launch(void* const* d_in, const int* in_sizes, int n_in,
                              void* d_out, int out_size, void* d_ws, size_t ws_size,
                              hipStream_t stream) {
  const float* p0 = (const float*)d_in[0];
  const float* p1 = (const float*)d_in[1];
  const float* p2 = (const float*)d_in[2];
  const void* hp = d_in[3];
  const void* wp = d_in[4];

  char* ws = (char*)d_ws;
  float4*   selbox  = (float4*)(ws + 0);           // 16*1024*16 = 262144
  float4*   selboff = (float4*)(ws + 262144);      // 262144
  float4*   boxes   = (float4*)(ws + 524288);      // 16*8400*16 = 2150400
  uint64_t* rowmask = (uint64_t*)(ws + 2674688);   // 16*1024*16*8 = 2097152
  uint32_t* keys    = (uint32_t*)(ws + 4771840);   // 537600
  int*      labels  = (int*)(ws + 5309440);        // 537600
  float*    selscore= (float*)(ws + 5847040);      // 65536
  int*      sellab  = (int*)(ws + 5912576);        // 65536  (total ~5.98 MB)

  k_decode<<<(NB * NA + 255) / 256, 256, 0, stream>>>(p0, p1, p2, hp, wp,
                                                      boxes, labels, keys);
  dim3 rg((NA + 511) / 512, NB);
  k_rank<<<rg, 256, 0, stream>>>(keys, boxes, labels, selbox, selboff,
                                 selscore, sellab);
  dim3 ig(KPRE / 16, NB);
  k_iou<<<ig, 256, 0, stream>>>(selboff, rowmask);
  k_scan<<<NB, 64, 0, stream>>>(rowmask, (const float*)selbox, selscore,
                                sellab, (float*)d_out);
}